// Round 5
// baseline (2032.344 us; speedup 1.0000x reference)
//
#include <hip/hip_runtime.h>
#include <hip/hip_bf16.h>

#define HID   512
#define BATCH 64
#define SRC   2048
#define MROWS (BATCH * SRC)

typedef __bf16 bf16x8 __attribute__((ext_vector_type(8)));
typedef __bf16 bf16x4 __attribute__((ext_vector_type(4)));
typedef float  f32x16 __attribute__((ext_vector_type(16)));

#define PANEL 520          // elems per A panel (512 + 8 skew) = 1040 B

__device__ inline float fast_tanh(float x) {
    float e = __builtin_amdgcn_exp2f(x * 2.8853900817779268f);
    return 1.0f - 2.0f * __builtin_amdgcn_rcpf(e + 1.0f);
}

template <int CTRL>
__device__ inline float dpp_add(float x) {
    int y = __builtin_amdgcn_update_dpp(0, __builtin_bit_cast(int, x), CTRL, 0xF, 0xF, true);
    return x + __builtin_bit_cast(float, y);
}

// sum over the 32 lanes of each 32-lane half (cols of the MFMA tile)
__device__ inline float reduce32(float x) {
    x = dpp_add<0xB1>(x);    // quad_perm [1,0,3,2]  (xor 1)
    x = dpp_add<0x4E>(x);    // quad_perm [2,3,0,1]  (xor 2)
    x = dpp_add<0x141>(x);   // row_half_mirror      (xor 4 equiv)
    x = dpp_add<0x140>(x);   // row_mirror           (xor 8 equiv)
    int y = __builtin_amdgcn_ds_swizzle(__builtin_bit_cast(int, x), 0x401F); // xor 16
    return x + __builtin_bit_cast(float, y);
}

// ---- shared building blocks (identical math to attn_main) ----
__device__ inline void stage_pass(const float* __restrict__ enc, __bf16* AL,
                                  int rowBase, int tid) {
    const float4* encB = (const float4*)enc + (size_t)rowBase * 128;
    #pragma unroll
    for (int i = 0; i < 16; ++i) {
        int f = i * 512 + tid;
        float4 v = encB[f];
        int row = f >> 7;
        int kq  = (f & 127) << 2;
        int kt = kq >> 4, half = (kq >> 3) & 1, j = kq & 7;
        int off = (kt * 2 + (row >> 5)) * PANEL + ((row & 31) + 32 * half) * 8 + j;
        bf16x4 o4;
        o4[0]=(__bf16)v.x; o4[1]=(__bf16)v.y; o4[2]=(__bf16)v.z; o4[3]=(__bf16)v.w;
        *(bf16x4*)&AL[off] = o4;
    }
}

__device__ inline void kloop32(const __bf16* pA, const char* BpkB, int rot,
                               f32x16& acc00, f32x16& acc01,
                               f32x16& acc10, f32x16& acc11) {
    bf16x8 q00 = *(const bf16x8*)(BpkB + (size_t)((rot + 0) & 31) * 16384);
    bf16x8 q01 = *(const bf16x8*)(BpkB + (size_t)((rot + 0) & 31) * 16384 + 1024);
    bf16x8 q10 = *(const bf16x8*)(BpkB + (size_t)((rot + 1) & 31) * 16384);
    bf16x8 q11 = *(const bf16x8*)(BpkB + (size_t)((rot + 1) & 31) * 16384 + 1024);
    bf16x8 q20 = *(const bf16x8*)(BpkB + (size_t)((rot + 2) & 31) * 16384);
    bf16x8 q21 = *(const bf16x8*)(BpkB + (size_t)((rot + 2) & 31) * 16384 + 1024);
    bf16x8 q30 = *(const bf16x8*)(BpkB + (size_t)((rot + 3) & 31) * 16384);
    bf16x8 q31 = *(const bf16x8*)(BpkB + (size_t)((rot + 3) & 31) * 16384 + 1024);
#define KSTEP(P0, P1, KK)                                                     \
    {                                                                         \
        int ia = (kt + (KK) + rot) & 31;                                      \
        const __bf16* pa = pA + ia * (2 * PANEL);                             \
        bf16x8 a0 = *(const bf16x8*)pa;                                       \
        bf16x8 a1 = *(const bf16x8*)(pa + PANEL);                             \
        acc00 = __builtin_amdgcn_mfma_f32_32x32x16_bf16(a0, P0, acc00, 0, 0, 0); \
        acc10 = __builtin_amdgcn_mfma_f32_32x32x16_bf16(a1, P0, acc10, 0, 0, 0); \
        acc01 = __builtin_amdgcn_mfma_f32_32x32x16_bf16(a0, P1, acc01, 0, 0, 0); \
        acc11 = __builtin_amdgcn_mfma_f32_32x32x16_bf16(a1, P1, acc11, 0, 0, 0); \
        int ip = (kt + (KK) + 4 + rot) & 31;                                  \
        P0 = *(const bf16x8*)(BpkB + (size_t)ip * 16384);                     \
        P1 = *(const bf16x8*)(BpkB + (size_t)ip * 16384 + 1024);              \
    }
    #pragma unroll
    for (int kt = 0; kt < 32; kt += 4) {
        KSTEP(q00, q01, 0)
        KSTEP(q10, q11, 1)
        KSTEP(q20, q21, 2)
        KSTEP(q30, q31, 3)
    }
#undef KSTEP
}

// ---- kernel 1 (fused prep): blocks 0-127 pack W1 -> bf16 fragment order;
//      blocks 128-191: bias_comb[b,o] = h[b]·W2[o,:] + W2_b[o] + W1_b[o]
__global__ void prep(const float* __restrict__ W1w, __bf16* __restrict__ Bpk,
                     const float* __restrict__ h, const float* __restrict__ W2w,
                     const float* __restrict__ W2b, const float* __restrict__ W1b,
                     float* __restrict__ biasc) {
    __shared__ float hh[HID];
    int tid = threadIdx.x;
    if (blockIdx.x < 128) {
        int t = blockIdx.x * 256 + tid;
        int l = t & 63, tile = t >> 6;
        int ot = tile & 15, kt = tile >> 4;
        int o = ot * 32 + (l & 31);
        int k = kt * 16 + (l >> 5) * 8;
        const float* src = W1w + (size_t)o * HID + k;
        float4 v0 = *(const float4*)src;
        float4 v1 = *(const float4*)(src + 4);
        bf16x8 r;
        r[0]=(__bf16)v0.x; r[1]=(__bf16)v0.y; r[2]=(__bf16)v0.z; r[3]=(__bf16)v0.w;
        r[4]=(__bf16)v1.x; r[5]=(__bf16)v1.y; r[6]=(__bf16)v1.z; r[7]=(__bf16)v1.w;
        ((bf16x8*)Bpk)[t] = r;
    } else {
        int b = blockIdx.x - 128;
        hh[tid]       = h[b * HID + tid];
        hh[tid + 256] = h[b * HID + tid + 256];
        __syncthreads();
        const float4* h4 = (const float4*)hh;
        for (int o = tid; o < HID; o += 256) {
            const float4* w4 = (const float4*)(W2w + (size_t)o * HID);
            float s = 0.f;
            #pragma unroll 8
            for (int k = 0; k < HID / 4; ++k) {
                float4 a = h4[k]; float4 w = w4[k];
                s += a.x * w.x + a.y * w.y + a.z * w.z + a.w * w.w;
            }
            biasc[b * HID + o] = s + W2b[o] + W1b[o];
        }
    }
}

// ==== PROBE 1: staging phase only, x12 (different tiles, barrier each) ====
__global__ __launch_bounds__(512, 4) void probe_stage(const float* __restrict__ enc,
                                                      float* __restrict__ sink) {
    __shared__ __bf16 AL[64 * PANEL];
    const int tid = threadIdx.x;
    #pragma unroll 1
    for (int p = 0; p < 12; ++p) {
        int tt = (blockIdx.x + p * 64) & 2047;     // wrap: always in-bounds
        stage_pass(enc, AL, tt * 64, tid);
        __syncthreads();
    }
    sink[blockIdx.x * 512 + tid] = (float)AL[tid] + (float)AL[tid + 8192]; // keep live
}

// ==== PROBE 2: K-loop only, x12 (accs chained across passes -> no DCE) ====
__global__ __launch_bounds__(512, 4) void probe_kloop(const __bf16* __restrict__ Bpk,
                                                      float* __restrict__ sink) {
    __shared__ __bf16 AL[64 * PANEL];
    const int tid = threadIdx.x;
    const int lane = tid & 63, wv = tid >> 6;
    for (int i = tid; i < 64 * PANEL / 4; i += 512) {   // cheap deterministic init
        bf16x4 o4;
        o4[0]=(__bf16)0.5f; o4[1]=(__bf16)-0.25f; o4[2]=(__bf16)0.125f; o4[3]=(__bf16)1.0f;
        *(bf16x4*)&AL[i * 4] = o4;
    }
    __syncthreads();
    const char* BpkB = (const char*)Bpk + (2 * wv) * 1024 + lane * 16;
    const __bf16* pA = AL + lane * 8;
    f32x16 acc00, acc01, acc10, acc11;
    #pragma unroll
    for (int i = 0; i < 16; ++i) { acc00[i]=0.f; acc01[i]=0.f; acc10[i]=0.f; acc11[i]=0.f; }
    #pragma unroll 1
    for (int p = 0; p < 12; ++p)
        kloop32(pA, BpkB, (blockIdx.x + p) & 31, acc00, acc01, acc10, acc11);
    float s = 0.f;
    #pragma unroll
    for (int r = 0; r < 16; ++r) s += acc00[r] + acc01[r] + acc10[r] + acc11[r];
    sink[blockIdx.x * 512 + tid] = s;
}

// ==== PROBE 3: K-loop + full epilogue, x12 ====
__global__ __launch_bounds__(512, 4) void probe_comp(const __bf16* __restrict__ Bpk,
                                                     const float* __restrict__ biasc,
                                                     const float* __restrict__ Vw,
                                                     float* __restrict__ sink) {
    __shared__ __bf16 AL[64 * PANEL];
    __shared__ float sred[64][9];
    const int tid = threadIdx.x;
    const int lane = tid & 63, wv = tid >> 6;
    const int col = lane & 31, hfi = lane >> 5;
    const int b = blockIdx.x >> 5;
    const int o0 = (2 * wv) * 32 + col, o1 = o0 + 32;
    const float bb0 = biasc[b * HID + o0], bb1 = biasc[b * HID + o1];
    const float vv0 = Vw[o0], vv1 = Vw[o1];
    for (int i = tid; i < 64 * PANEL / 4; i += 512) {
        bf16x4 o4;
        o4[0]=(__bf16)0.5f; o4[1]=(__bf16)-0.25f; o4[2]=(__bf16)0.125f; o4[3]=(__bf16)1.0f;
        *(bf16x4*)&AL[i * 4] = o4;
    }
    __syncthreads();
    const char* BpkB = (const char*)Bpk + (2 * wv) * 1024 + lane * 16;
    const __bf16* pA = AL + lane * 8;
    float ssum = 0.f;
    #pragma unroll 1
    for (int p = 0; p < 12; ++p) {
        f32x16 acc00, acc01, acc10, acc11;
        #pragma unroll
        for (int i = 0; i < 16; ++i) { acc00[i]=0.f; acc01[i]=0.f; acc10[i]=0.f; acc11[i]=0.f; }
        kloop32(pA, BpkB, (blockIdx.x + p) & 31, acc00, acc01, acc10, acc11);
        #pragma unroll
        for (int r = 0; r < 16; ++r) {
            float p0 = vv0 * fast_tanh(acc00[r] + bb0) + vv1 * fast_tanh(acc01[r] + bb1);
            float p1 = vv0 * fast_tanh(acc10[r] + bb0) + vv1 * fast_tanh(acc11[r] + bb1);
            p0 = reduce32(p0);
            p1 = reduce32(p1);
            if (col == 0) {
                int rl = (r & 3) + 8 * (r >> 2) + 4 * hfi;
                sred[rl][wv]      = p0;
                sred[32 + rl][wv] = p1;
            }
        }
        __syncthreads();
        if (tid < 64) {
            float s = 0.f;
            #pragma unroll
            for (int w = 0; w < 8; ++w) s += sred[tid][w];
            ssum += s;
        }
        __syncthreads();
    }
    sink[blockIdx.x * 512 + tid] = ssum;
}

// ---- kernel 2: REAL fused GEMM + tanh + V-dot (unchanged round-4 logic) ----
__global__ __launch_bounds__(512, 4) void attn_main(
        const float* __restrict__ enc, const __bf16* __restrict__ Bpk,
        const float* __restrict__ biasc, const float* __restrict__ Vw,
        float* __restrict__ scores) {
    __shared__ __bf16 AL[64 * PANEL];
    __shared__ float sred[64][9];

    const int tid = threadIdx.x;
    const int blockRow = blockIdx.x * 64;
    const int b = blockIdx.x >> 5;
    const int lane = tid & 63;
    const int wv = tid >> 6;
    const int col = lane & 31;
    const int hfi = lane >> 5;

    const int o0 = (2 * wv) * 32 + col;
    const int o1 = o0 + 32;
    float bb0 = biasc[b * HID + o0], bb1 = biasc[b * HID + o1];
    float vv0 = Vw[o0],               vv1 = Vw[o1];

    stage_pass(enc, AL, blockRow, tid);
    __syncthreads();

    const int rot = blockIdx.x & 31;
    const char* BpkB = (const char*)Bpk + (2 * wv) * 1024 + lane * 16;
    const __bf16* pA = AL + lane * 8;

    f32x16 acc00, acc01, acc10, acc11;
    #pragma unroll
    for (int i = 0; i < 16; ++i) { acc00[i]=0.f; acc01[i]=0.f; acc10[i]=0.f; acc11[i]=0.f; }

    kloop32(pA, BpkB, rot, acc00, acc01, acc10, acc11);

    #pragma unroll
    for (int r = 0; r < 16; ++r) {
        float p0 = vv0 * fast_tanh(acc00[r] + bb0) + vv1 * fast_tanh(acc01[r] + bb1);
        float p1 = vv0 * fast_tanh(acc10[r] + bb0) + vv1 * fast_tanh(acc11[r] + bb1);
        p0 = reduce32(p0);
        p1 = reduce32(p1);
        if (col == 0) {
            int rl = (r & 3) + 8 * (r >> 2) + 4 * hfi;
            sred[rl][wv]      = p0;
            sred[32 + rl][wv] = p1;
        }
    }
    __syncthreads();
    if (tid < 64) {
        float s = 0.f;
        #pragma unroll
        for (int w = 0; w < 8; ++w) s += sred[tid][w];
        scores[blockRow + tid] = s;
    }
}

// ---- kernel 3: in-place softmax over S=2048 per batch row ----
__global__ void softmax_k(float* __restrict__ scores) {
    int b = blockIdx.x;
    int tid = threadIdx.x;
    int lane = tid & 63, wv = tid >> 6;
    __shared__ float red[4];
    float* row = scores + (size_t)b * SRC;
    float4 v0 = *(float4*)(row + tid * 8);
    float4 v1 = *(float4*)(row + tid * 8 + 4);
    float x[8] = {v0.x, v0.y, v0.z, v0.w, v1.x, v1.y, v1.z, v1.w};
    float mx = x[0];
    #pragma unroll
    for (int r = 1; r < 8; ++r) mx = fmaxf(mx, x[r]);
    #pragma unroll
    for (int m = 1; m <= 32; m <<= 1) mx = fmaxf(mx, __shfl_xor(mx, m, 64));
    if (lane == 0) red[wv] = mx;
    __syncthreads();
    mx = fmaxf(fmaxf(red[0], red[1]), fmaxf(red[2], red[3]));
    __syncthreads();
    float s = 0.f;
    #pragma unroll
    for (int r = 0; r < 8; ++r) {
        x[r] = __builtin_amdgcn_exp2f((x[r] - mx) * 1.44269504088896f);
        s += x[r];
    }
    #pragma unroll
    for (int m = 1; m <= 32; m <<= 1) s += __shfl_xor(s, m, 64);
    if (lane == 0) red[wv] = s;
    __syncthreads();
    s = red[0] + red[1] + red[2] + red[3];
    float inv = 1.0f / s;
    float4 o0 = make_float4(x[0] * inv, x[1] * inv, x[2] * inv, x[3] * inv);
    float4 o1 = make_float4(x[4] * inv, x[5] * inv, x[6] * inv, x[7] * inv);
    *(float4*)(row + tid * 8)     = o0;
    *(float4*)(row + tid * 8 + 4) = o1;
}

extern "C" void kernel_launch(void* const* d_in, const int* in_sizes, int n_in,
                              void* d_out, int out_size, void* d_ws, size_t ws_size,
                              hipStream_t stream) {
    const float* h    = (const float*)d_in[0];
    const float* enc  = (const float*)d_in[1];
    const float* W1w  = (const float*)d_in[2];
    const float* W1b  = (const float*)d_in[3];
    const float* W2w  = (const float*)d_in[4];
    const float* W2b  = (const float*)d_in[5];
    const float* Vw   = (const float*)d_in[6];
    float* out = (float*)d_out;

    __bf16* Bpk  = (__bf16*)d_ws;                                       // 512 KB
    float*  biasc = (float*)((char*)d_ws + HID * HID * sizeof(__bf16)); // 128 KB
    float*  sink  = (float*)((char*)d_ws + (1 << 20));                  // 4 MB scratch

    prep<<<192, 256, 0, stream>>>(W1w, Bpk, h, W2w, W2b, W1b, biasc);

    // --- measurement probes (write only to ws scratch; output unaffected) ---
    if (ws_size >= (1u << 20) + (size_t)MROWS * 8 * sizeof(float)) {
        probe_stage<<<MROWS / 64, 512, 0, stream>>>(enc, sink);
        probe_kloop<<<MROWS / 64, 512, 0, stream>>>(Bpk, sink);
        probe_comp <<<MROWS / 64, 512, 0, stream>>>(Bpk, biasc, Vw, sink);
    }

    attn_main<<<MROWS / 64, 512, 0, stream>>>(enc, Bpk, biasc, Vw, out);
    softmax_k<<<BATCH, 256, 0, stream>>>(out);
}

// Round 6
// 443.187 us; speedup vs baseline: 4.5857x; 4.5857x over previous
//
#include <hip/hip_runtime.h>
#include <hip/hip_bf16.h>

#define HID   512
#define BATCH 64
#define SRC   2048
#define MROWS (BATCH * SRC)

typedef __bf16 bf16x8 __attribute__((ext_vector_type(8)));
typedef __bf16 bf16x4 __attribute__((ext_vector_type(4)));
typedef float  f32x16 __attribute__((ext_vector_type(16)));

#define PANEL 520          // elems per A panel (512 + 8 skew) = 1040 B

__device__ inline float fast_tanh(float x) {
    float e = __builtin_amdgcn_exp2f(x * 2.8853900817779268f);
    return 1.0f - 2.0f * __builtin_amdgcn_rcpf(e + 1.0f);
}

template <int CTRL>
__device__ inline float dpp_add(float x) {
    int y = __builtin_amdgcn_update_dpp(0, __builtin_bit_cast(int, x), CTRL, 0xF, 0xF, true);
    return x + __builtin_bit_cast(float, y);
}

// sum over the 32 lanes of each 32-lane half (cols of the MFMA tile)
__device__ inline float reduce32(float x) {
    x = dpp_add<0xB1>(x);    // quad_perm [1,0,3,2]  (xor 1)
    x = dpp_add<0x4E>(x);    // quad_perm [2,3,0,1]  (xor 2)
    x = dpp_add<0x141>(x);   // row_half_mirror      (xor 4 equiv)
    x = dpp_add<0x140>(x);   // row_mirror           (xor 8 equiv)
    int y = __builtin_amdgcn_ds_swizzle(__builtin_bit_cast(int, x), 0x401F); // xor 16
    return x + __builtin_bit_cast(float, y);
}

// ---- kernel 1 (fused prep): blocks 0-127 pack W1 -> bf16 fragment order;
//      blocks 128-191: bias_comb[b,o] = h[b]·W2[o,:] + W2_b[o] + W1_b[o]
__global__ void prep(const float* __restrict__ W1w, __bf16* __restrict__ Bpk,
                     const float* __restrict__ h, const float* __restrict__ W2w,
                     const float* __restrict__ W2b, const float* __restrict__ W1b,
                     float* __restrict__ biasc) {
    __shared__ float hh[HID];
    int tid = threadIdx.x;
    if (blockIdx.x < 128) {
        int t = blockIdx.x * 256 + tid;
        int l = t & 63, tile = t >> 6;
        int ot = tile & 15, kt = tile >> 4;
        int o = ot * 32 + (l & 31);
        int k = kt * 16 + (l >> 5) * 8;
        const float* src = W1w + (size_t)o * HID + k;
        float4 v0 = *(const float4*)src;
        float4 v1 = *(const float4*)(src + 4);
        bf16x8 r;
        r[0]=(__bf16)v0.x; r[1]=(__bf16)v0.y; r[2]=(__bf16)v0.z; r[3]=(__bf16)v0.w;
        r[4]=(__bf16)v1.x; r[5]=(__bf16)v1.y; r[6]=(__bf16)v1.z; r[7]=(__bf16)v1.w;
        ((bf16x8*)Bpk)[t] = r;
    } else {
        int b = blockIdx.x - 128;
        hh[tid]       = h[b * HID + tid];
        hh[tid + 256] = h[b * HID + tid + 256];
        __syncthreads();
        const float4* h4 = (const float4*)hh;
        for (int o = tid; o < HID; o += 256) {
            const float4* w4 = (const float4*)(W2w + (size_t)o * HID);
            float s = 0.f;
            #pragma unroll 8
            for (int k = 0; k < HID / 4; ++k) {
                float4 a = h4[k]; float4 w = w4[k];
                s += a.x * w.x + a.y * w.y + a.z * w.z + a.w * w.w;
            }
            biasc[b * HID + o] = s + W2b[o] + W1b[o];
        }
    }
}

// ---- kernel 2: fused GEMM + tanh + V-dot. Split-o K-loop:
// phase1 = MFMA sweep of o-block0 (b0); phase2 = MFMA sweep of o-block1 (b1)
// with the o0-half of the tanh epilogue interleaved (MFMA pipe || VALU pipe);
// phase3 = remaining tanh + DPP reduction. B L2 traffic unchanged (each
// o-block's B panel is swept exactly once).
__global__ __launch_bounds__(512, 4) void attn_main(
        const float* __restrict__ enc, const __bf16* __restrict__ Bpk,
        const float* __restrict__ biasc, const float* __restrict__ Vw,
        float* __restrict__ scores) {
    __shared__ __bf16 AL[64 * PANEL];     // 64 panels x 1040 B = 66560 B
    __shared__ float sred[64][9];

    const int tid = threadIdx.x;
    const int blockRow = blockIdx.x * 64;
    const int b = blockIdx.x >> 5;
    const int lane = tid & 63;
    const int wv = tid >> 6;
    const int col = lane & 31;
    const int hfi = lane >> 5;

    // epilogue constants
    const int o0 = (2 * wv) * 32 + col;
    const int o1 = o0 + 32;
    float bb0 = biasc[b * HID + o0], bb1 = biasc[b * HID + o1];
    float vv0 = Vw[o0],               vv1 = Vw[o1];

    // ---- stage A: 64 rows x 512 k fp32 -> bf16 fragment order in LDS ----
    const float4* encB = (const float4*)enc + (size_t)blockRow * 128;
    #pragma unroll
    for (int i = 0; i < 16; ++i) {
        int f = i * 512 + tid;           // coalesced 1KB/wave
        float4 v = encB[f];
        int row = f >> 7;
        int kq  = (f & 127) << 2;
        int kt = kq >> 4, half = (kq >> 3) & 1, j = kq & 7;
        int off = (kt * 2 + (row >> 5)) * PANEL + ((row & 31) + 32 * half) * 8 + j;
        bf16x4 o4;
        o4[0]=(__bf16)v.x; o4[1]=(__bf16)v.y; o4[2]=(__bf16)v.z; o4[3]=(__bf16)v.w;
        *(bf16x4*)&AL[off] = o4;
    }
    __syncthreads();                      // only barrier before epilogue

    const int rot = blockIdx.x & 31;
    const char* BpkB = (const char*)Bpk + (2 * wv) * 1024 + lane * 16;
    const __bf16* pA = AL + lane * 8;

    f32x16 acc00, acc01, acc10, acc11;
    #pragma unroll
    for (int i = 0; i < 16; ++i) { acc00[i]=0.f; acc01[i]=0.f; acc10[i]=0.f; acc11[i]=0.f; }

    // ======== phase 1: k-sweep over o-block 0 (b0 only), MFMA-dense ========
    bf16x8 u0 = *(const bf16x8*)(BpkB + (size_t)((rot + 0) & 31) * 16384);
    bf16x8 u1 = *(const bf16x8*)(BpkB + (size_t)((rot + 1) & 31) * 16384);
    bf16x8 u2 = *(const bf16x8*)(BpkB + (size_t)((rot + 2) & 31) * 16384);
    bf16x8 u3 = *(const bf16x8*)(BpkB + (size_t)((rot + 3) & 31) * 16384);

#define KS0(P, KK)                                                            \
    {                                                                         \
        int ia = ((KK) + rot) & 31;                                           \
        const __bf16* pa = pA + ia * (2 * PANEL);                             \
        bf16x8 a0 = *(const bf16x8*)pa;                                       \
        bf16x8 a1 = *(const bf16x8*)(pa + PANEL);                             \
        acc00 = __builtin_amdgcn_mfma_f32_32x32x16_bf16(a0, P, acc00, 0, 0, 0); \
        acc10 = __builtin_amdgcn_mfma_f32_32x32x16_bf16(a1, P, acc10, 0, 0, 0); \
        int ip = ((KK) + 4 + rot) & 31;  /* wrap: valid mem, unused */        \
        P = *(const bf16x8*)(BpkB + (size_t)ip * 16384);                      \
    }
    #pragma unroll
    for (int g = 0; g < 8; ++g) {
        KS0(u0, 4 * g + 0)
        KS0(u1, 4 * g + 1)
        KS0(u2, 4 * g + 2)
        KS0(u3, 4 * g + 3)
    }
#undef KS0

    // ======== phase 2: k-sweep over o-block 1 (b1) || epilogue-half-A ======
    // acc00/acc10 are final: overwrite in place with vv0*tanh(.+bb0) while
    // the b1 MFMAs stream — VALU work hides under the MFMA pipe.
    u0 = *(const bf16x8*)(BpkB + (size_t)((rot + 0) & 31) * 16384 + 1024);
    u1 = *(const bf16x8*)(BpkB + (size_t)((rot + 1) & 31) * 16384 + 1024);
    u2 = *(const bf16x8*)(BpkB + (size_t)((rot + 2) & 31) * 16384 + 1024);
    u3 = *(const bf16x8*)(BpkB + (size_t)((rot + 3) & 31) * 16384 + 1024);

#define KS1(P, KK)                                                            \
    {                                                                         \
        int ia = ((KK) + rot) & 31;                                           \
        const __bf16* pa = pA + ia * (2 * PANEL);                             \
        bf16x8 a0 = *(const bf16x8*)pa;                                       \
        bf16x8 a1 = *(const bf16x8*)(pa + PANEL);                             \
        acc01 = __builtin_amdgcn_mfma_f32_32x32x16_bf16(a0, P, acc01, 0, 0, 0); \
        acc11 = __builtin_amdgcn_mfma_f32_32x32x16_bf16(a1, P, acc11, 0, 0, 0); \
        int ip = ((KK) + 4 + rot) & 31;                                       \
        P = *(const bf16x8*)(BpkB + (size_t)ip * 16384 + 1024);               \
    }
#define EPIA(R)                                                               \
    {                                                                         \
        acc00[R] = vv0 * fast_tanh(acc00[R] + bb0);                           \
        acc10[R] = vv0 * fast_tanh(acc10[R] + bb0);                           \
    }
    #pragma unroll
    for (int g = 0; g < 8; ++g) {
        KS1(u0, 4 * g + 0)
        KS1(u1, 4 * g + 1)
        EPIA(2 * g + 0)
        KS1(u2, 4 * g + 2)
        KS1(u3, 4 * g + 3)
        EPIA(2 * g + 1)
    }
#undef KS1
#undef EPIA

    // ======== phase 3: finish epilogue + DPP 32-lane reduction =============
    // C layout: col = lane&31, row = (r&3) + 8*(r>>2) + 4*(lane>>5)
    #pragma unroll
    for (int r = 0; r < 16; ++r) {
        float s0 = acc00[r] + vv1 * fast_tanh(acc01[r] + bb1);
        float s1 = acc10[r] + vv1 * fast_tanh(acc11[r] + bb1);
        s0 = reduce32(s0);
        s1 = reduce32(s1);
        if (col == 0) {
            int rl = (r & 3) + 8 * (r >> 2) + 4 * hfi;
            sred[rl][wv]      = s0;
            sred[32 + rl][wv] = s1;
        }
    }
    __syncthreads();
    if (tid < 64) {
        float s = 0.f;
        #pragma unroll
        for (int w = 0; w < 8; ++w) s += sred[tid][w];
        scores[blockRow + tid] = s;       // V_b omitted: cancels in softmax
    }
}

// ---- kernel 3: in-place softmax over S=2048 per batch row ----
__global__ void softmax_k(float* __restrict__ scores) {
    int b = blockIdx.x;
    int tid = threadIdx.x;
    int lane = tid & 63, wv = tid >> 6;
    __shared__ float red[4];
    float* row = scores + (size_t)b * SRC;
    float4 v0 = *(float4*)(row + tid * 8);
    float4 v1 = *(float4*)(row + tid * 8 + 4);
    float x[8] = {v0.x, v0.y, v0.z, v0.w, v1.x, v1.y, v1.z, v1.w};
    float mx = x[0];
    #pragma unroll
    for (int r = 1; r < 8; ++r) mx = fmaxf(mx, x[r]);
    #pragma unroll
    for (int m = 1; m <= 32; m <<= 1) mx = fmaxf(mx, __shfl_xor(mx, m, 64));
    if (lane == 0) red[wv] = mx;
    __syncthreads();
    mx = fmaxf(fmaxf(red[0], red[1]), fmaxf(red[2], red[3]));
    __syncthreads();
    float s = 0.f;
    #pragma unroll
    for (int r = 0; r < 8; ++r) {
        x[r] = __builtin_amdgcn_exp2f((x[r] - mx) * 1.44269504088896f);
        s += x[r];
    }
    #pragma unroll
    for (int m = 1; m <= 32; m <<= 1) s += __shfl_xor(s, m, 64);
    if (lane == 0) red[wv] = s;
    __syncthreads();
    s = red[0] + red[1] + red[2] + red[3];
    float inv = 1.0f / s;
    float4 o0 = make_float4(x[0] * inv, x[1] * inv, x[2] * inv, x[3] * inv);
    float4 o1 = make_float4(x[4] * inv, x[5] * inv, x[6] * inv, x[7] * inv);
    *(float4*)(row + tid * 8)     = o0;
    *(float4*)(row + tid * 8 + 4) = o1;
}

extern "C" void kernel_launch(void* const* d_in, const int* in_sizes, int n_in,
                              void* d_out, int out_size, void* d_ws, size_t ws_size,
                              hipStream_t stream) {
    const float* h    = (const float*)d_in[0];
    const float* enc  = (const float*)d_in[1];
    const float* W1w  = (const float*)d_in[2];
    const float* W1b  = (const float*)d_in[3];
    const float* W2w  = (const float*)d_in[4];
    const float* W2b  = (const float*)d_in[5];
    const float* Vw   = (const float*)d_in[6];
    // d_in[7] = V_b: constant shift cancels in softmax.
    float* out = (float*)d_out;

    __bf16* Bpk  = (__bf16*)d_ws;                                       // 512 KB
    float*  biasc = (float*)((char*)d_ws + HID * HID * sizeof(__bf16)); // 128 KB

    prep     <<<192, 256, 0, stream>>>(W1w, Bpk, h, W2w, W2b, W1b, biasc);
    attn_main<<<MROWS / 64, 512, 0, stream>>>(enc, Bpk, biasc, Vw, out);
    softmax_k<<<BATCH, 256, 0, stream>>>(out);
}